// Round 1
// baseline (341.989 us; speedup 1.0000x reference)
//
#include <hip/hip_runtime.h>
#include <stdint.h>

#define M_DIM 4096
#define N_DIM 4096
#define K_DIM 4096

#define BM 128
#define BN 128
#define BK 32

typedef __bf16 bf16x8 __attribute__((ext_vector_type(8)));
typedef float f32x4 __attribute__((ext_vector_type(4)));

// round-to-nearest-even fp32 -> bf16 bits
__device__ __forceinline__ unsigned short f2bf(float f) {
    unsigned u = __builtin_bit_cast(unsigned, f);
    u = (u + 0x7FFFu + ((u >> 16) & 1u)) >> 16;
    return (unsigned short)u;
}

// ---------------------------------------------------------------- conversion
// A fp32 [M][K] -> bf16 bits, same layout. n4 = elements/4.
__global__ __launch_bounds__(256) void cvt_bf16(const float* __restrict__ in,
                                                unsigned short* __restrict__ out,
                                                int n4) {
    int i = blockIdx.x * 256 + threadIdx.x;
    if (i >= n4) return;
    const float4 v = ((const float4*)in)[i];
    ushort4 o;
    o.x = f2bf(v.x);
    o.y = f2bf(v.y);
    o.z = f2bf(v.z);
    o.w = f2bf(v.w);
    ((ushort4*)out)[i] = o;
}

// W fp32 [K][N] -> Wt bf16 [N][K]  (Wt[n][k] = W[k][n]); 64x64 tiles
__global__ __launch_bounds__(256) void transpose_cvt(const float* __restrict__ W,
                                                     unsigned short* __restrict__ Wt) {
    __shared__ float tile[64][65];
    const int n0 = blockIdx.x * 64;
    const int k0 = blockIdx.y * 64;
    const int c = threadIdx.x & 63;
    const int r4 = threadIdx.x >> 6;  // wave id, 0..3
#pragma unroll
    for (int rr = 0; rr < 16; ++rr) {
        int row = r4 * 16 + rr;  // k offset within tile
        tile[row][c] = W[(size_t)(k0 + row) * N_DIM + (n0 + c)];
    }
    __syncthreads();
#pragma unroll
    for (int rr = 0; rr < 16; ++rr) {
        int nrow = r4 * 16 + rr;  // n offset within tile
        Wt[(size_t)(n0 + nrow) * K_DIM + (k0 + c)] = f2bf(tile[c][nrow]);
    }
}

// ---------------------------------------------------------------- GEMM (m97 recipe)
__device__ __forceinline__ void load_lds16(const void* g, void* l) {
    __builtin_amdgcn_global_load_lds(
        (const __attribute__((address_space(1))) void*)g,
        (__attribute__((address_space(3))) void*)l,
        16, 0, 0);
}

// C[m][n] = sum_k A[m][k] * Bt[n][k] + bias[n]; A,Bt bf16 bits, C fp32
__global__ __launch_bounds__(256) void gemm_bf16(const unsigned short* __restrict__ A,
                                                 const unsigned short* __restrict__ Bt,
                                                 const float* __restrict__ bias,
                                                 float* __restrict__ C) {
    __shared__ __align__(16) unsigned short As[BM * BK];  // [128][32], row-major, no pad
    __shared__ __align__(16) unsigned short Bs[BN * BK];  // [128][32]

    const int tid = threadIdx.x;
    const int lane = tid & 63;
    const int wave = tid >> 6;
    const int m0 = blockIdx.y * BM;
    const int n0 = blockIdx.x * BN;
    const int wm = (wave >> 1) * 64;
    const int wn = (wave & 1) * 64;
    const int lrow = lane & 15;
    const int quad = lane >> 4;
    const int koff = quad * 8;

    f32x4 acc[4][4] = {};

    // staging map: chunk g in [0,512): row = g>>2 (64B rows), chunk = g&3 (16B)
    const int r0 = tid >> 2;
    const int c0 = tid & 3;
    const unsigned short* agp0 = A + (size_t)(m0 + r0) * K_DIM + c0 * 8;
    const unsigned short* agp1 = A + (size_t)(m0 + 64 + r0) * K_DIM + c0 * 8;
    const unsigned short* bgp0 = Bt + (size_t)(n0 + r0) * K_DIM + c0 * 8;
    const unsigned short* bgp1 = Bt + (size_t)(n0 + 64 + r0) * K_DIM + c0 * 8;
    unsigned short* al0 = As + tid * 8;          // byte off = tid*16
    unsigned short* al1 = As + (256 + tid) * 8;  // byte off = (256+tid)*16
    unsigned short* bl0 = Bs + tid * 8;
    unsigned short* bl1 = Bs + (256 + tid) * 8;

    for (int k0 = 0; k0 < K_DIM; k0 += BK) {
        load_lds16(agp0 + k0, al0);
        load_lds16(agp1 + k0, al1);
        load_lds16(bgp0 + k0, bl0);
        load_lds16(bgp1 + k0, bl1);
        __syncthreads();  // drains vmcnt -> staged data visible

        bf16x8 af[4], bf[4];
#pragma unroll
        for (int i = 0; i < 4; ++i)
            af[i] = *(const bf16x8*)(As + (wm + i * 16 + lrow) * BK + koff);
#pragma unroll
        for (int j = 0; j < 4; ++j)
            bf[j] = *(const bf16x8*)(Bs + (wn + j * 16 + lrow) * BK + koff);
#pragma unroll
        for (int i = 0; i < 4; ++i)
#pragma unroll
            for (int j = 0; j < 4; ++j)
                acc[i][j] = __builtin_amdgcn_mfma_f32_16x16x32_bf16(af[i], bf[j], acc[i][j], 0, 0, 0);
        __syncthreads();  // before next tile overwrites LDS
    }

    // C/D layout: col = lane&15, row = quad*4 + reg   [measured m89/m91]
#pragma unroll
    for (int j = 0; j < 4; ++j) {
        const int col = n0 + wn + j * 16 + lrow;
        const float bj = bias[col];
#pragma unroll
        for (int i = 0; i < 4; ++i) {
            const int rbase = m0 + wm + i * 16 + quad * 4;
#pragma unroll
            for (int r = 0; r < 4; ++r)
                C[(size_t)(rbase + r) * N_DIM + col] = acc[i][j][r] + bj;
        }
    }
}

// ---------------------------------------------------------------- fallback (ws too small)
__global__ __launch_bounds__(256) void naive_gemm(const float* __restrict__ A,
                                                  const float* __restrict__ W,
                                                  const float* __restrict__ bias,
                                                  float* __restrict__ C) {
    const int col = blockIdx.x * 16 + threadIdx.x;
    const int row = blockIdx.y * 16 + threadIdx.y;
    float s = 0.f;
    for (int k = 0; k < K_DIM; ++k)
        s += A[(size_t)row * K_DIM + k] * W[(size_t)k * N_DIM + col];
    C[(size_t)row * N_DIM + col] = s + bias[col];
}

extern "C" void kernel_launch(void* const* d_in, const int* in_sizes, int n_in,
                              void* d_out, int out_size, void* d_ws, size_t ws_size,
                              hipStream_t stream) {
    const float* A = (const float*)d_in[0];     // sparse [4096,4096] fp32
    const float* W = (const float*)d_in[1];     // weight [4096,4096] fp32 (K-major rows)
    const float* bias = (const float*)d_in[2];  // [4096] fp32
    float* out = (float*)d_out;

    const size_t need = (size_t)2 * M_DIM * K_DIM * sizeof(unsigned short);  // 67 MB
    if (ws_size >= need) {
        unsigned short* Abf = (unsigned short*)d_ws;
        unsigned short* Wt = Abf + (size_t)M_DIM * K_DIM;

        cvt_bf16<<<(M_DIM * K_DIM / 4 + 255) / 256, 256, 0, stream>>>(A, Abf, M_DIM * K_DIM / 4);
        transpose_cvt<<<dim3(N_DIM / 64, K_DIM / 64), 256, 0, stream>>>(W, Wt);
        gemm_bf16<<<dim3(N_DIM / BN, M_DIM / BM), 256, 0, stream>>>(Abf, Wt, bias, out);
    } else {
        naive_gemm<<<dim3(N_DIM / 16, M_DIM / 16), dim3(16, 16), 0, stream>>>(A, W, bias, out);
    }
}

// Round 2
// 338.721 us; speedup vs baseline: 1.0096x; 1.0096x over previous
//
#include <hip/hip_runtime.h>
#include <stdint.h>

#define M_DIM 4096
#define N_DIM 4096
#define K_DIM 4096

#define BM 128
#define BN 128
#define BK 32

typedef __bf16 bf16x8 __attribute__((ext_vector_type(8)));
typedef float f32x4 __attribute__((ext_vector_type(4)));
typedef unsigned short us8 __attribute__((ext_vector_type(8)));

// round-to-nearest-even fp32 -> bf16 bits
__device__ __forceinline__ unsigned short f2bf(float f) {
    unsigned u = __builtin_bit_cast(unsigned, f);
    u = (u + 0x7FFFu + ((u >> 16) & 1u)) >> 16;
    return (unsigned short)u;
}

// ---------------------------------------------------------------- fused prep
// One block does: (a) convert 4096 consecutive floats of A -> bf16 (same layout)
//                 (b) transpose+convert one 64x64 tile of W -> Wt[n][k] bf16
// grid = 4096 blocks (A: 4096*4096 / 4096 per block; W: 64x64 tiles = 4096)
__global__ __launch_bounds__(256) void prep(const float* __restrict__ A,
                                            unsigned short* __restrict__ Abf,
                                            const float* __restrict__ W,
                                            unsigned short* __restrict__ Wt) {
    const int b = blockIdx.x;
    const int tid = threadIdx.x;

    // ---- part (a): A convert, float4 in / ushort4 out, fully coalesced
#pragma unroll
    for (int it = 0; it < 4; ++it) {
        const int i = b * 1024 + it * 256 + tid;  // float4 index
        const float4 v = ((const float4*)A)[i];
        ushort4 o;
        o.x = f2bf(v.x);
        o.y = f2bf(v.y);
        o.z = f2bf(v.z);
        o.w = f2bf(v.w);
        ((ushort4*)Abf)[i] = o;
    }

    // ---- part (b): W transpose tile. tile index: n-tile fastest
    __shared__ float tile[64][65];  // pad 65: store stride-1, read stride-65 (bank-free)
    const int n0 = (b & 63) * 64;
    const int k0 = (b >> 6) * 64;
    const int c = tid & 63;
    const int r4 = tid >> 6;
#pragma unroll
    for (int rr = 0; rr < 16; ++rr) {
        const int row = r4 * 16 + rr;  // k offset in tile
        tile[row][c] = W[(size_t)(k0 + row) * N_DIM + (n0 + c)];
    }
    __syncthreads();
    // writes: 16B/lane, 8 bf16 along k. lanes 0..7 cover one n-row's 64 k.
    const int kc = tid & 7;
#pragma unroll
    for (int half = 0; half < 2; ++half) {
        const int nrow = (tid >> 3) + half * 32;
        us8 o;
#pragma unroll
        for (int i = 0; i < 8; ++i) o[i] = f2bf(tile[kc * 8 + i][nrow]);
        *(us8*)(Wt + (size_t)(n0 + nrow) * K_DIM + k0 + kc * 8) = o;
    }
}

// ---------------------------------------------------------------- GEMM (m97 recipe + XCD swizzle)
__device__ __forceinline__ void load_lds16(const void* g, void* l) {
    __builtin_amdgcn_global_load_lds(
        (const __attribute__((address_space(1))) void*)g,
        (__attribute__((address_space(3))) void*)l,
        16, 0, 0);
}

// C[m][n] = sum_k A[m][k] * Bt[n][k] + bias[n]; A,Bt bf16 bits, C fp32
__global__ __launch_bounds__(256) void gemm_bf16(const unsigned short* __restrict__ A,
                                                 const unsigned short* __restrict__ Bt,
                                                 const float* __restrict__ bias,
                                                 float* __restrict__ C) {
    __shared__ __align__(16) unsigned short As[BM * BK];  // [128][32], no pad (global_load_lds)
    __shared__ __align__(16) unsigned short Bs[BN * BK];

    // XCD-aware supertile swizzle: 32x32 block grid as 4x4 supertiles of 8x8.
    // Assume round-robin bid->XCD (bid&7). XCD x runs supertile x then x+8, so
    // ~64 co-resident blocks per XCD share 8 A-panels + 8 B-panels (16 MB,
    // k-synchronized slices) -> L2-hit staging loads.
    const int bid = blockIdx.x;
    const int xcd = bid & 7;
    const int i_ = bid >> 3;                 // 0..127 within XCD
    const int st = xcd + 8 * (i_ >> 6);      // supertile 0..15
    const int within = i_ & 63;
    const int m0 = ((st >> 2) * 8 + (within >> 3)) * BM;
    const int n0 = ((st & 3) * 8 + (within & 7)) * BN;

    const int tid = threadIdx.x;
    const int lane = tid & 63;
    const int wave = tid >> 6;
    const int wm = (wave >> 1) * 64;
    const int wn = (wave & 1) * 64;
    const int lrow = lane & 15;
    const int quad = lane >> 4;
    const int koff = quad * 8;

    f32x4 acc[4][4] = {};

    const int r0 = tid >> 2;
    const int c0 = tid & 3;
    const unsigned short* agp0 = A + (size_t)(m0 + r0) * K_DIM + c0 * 8;
    const unsigned short* agp1 = A + (size_t)(m0 + 64 + r0) * K_DIM + c0 * 8;
    const unsigned short* bgp0 = Bt + (size_t)(n0 + r0) * K_DIM + c0 * 8;
    const unsigned short* bgp1 = Bt + (size_t)(n0 + 64 + r0) * K_DIM + c0 * 8;
    unsigned short* al0 = As + tid * 8;
    unsigned short* al1 = As + (256 + tid) * 8;
    unsigned short* bl0 = Bs + tid * 8;
    unsigned short* bl1 = Bs + (256 + tid) * 8;

    for (int k0 = 0; k0 < K_DIM; k0 += BK) {
        load_lds16(agp0 + k0, al0);
        load_lds16(agp1 + k0, al1);
        load_lds16(bgp0 + k0, bl0);
        load_lds16(bgp1 + k0, bl1);
        __syncthreads();

        bf16x8 af[4], bf[4];
#pragma unroll
        for (int i = 0; i < 4; ++i)
            af[i] = *(const bf16x8*)(As + (wm + i * 16 + lrow) * BK + koff);
#pragma unroll
        for (int j = 0; j < 4; ++j)
            bf[j] = *(const bf16x8*)(Bs + (wn + j * 16 + lrow) * BK + koff);
#pragma unroll
        for (int i = 0; i < 4; ++i)
#pragma unroll
            for (int j = 0; j < 4; ++j)
                acc[i][j] = __builtin_amdgcn_mfma_f32_16x16x32_bf16(af[i], bf[j], acc[i][j], 0, 0, 0);
        __syncthreads();
    }

    // C/D layout: col = lane&15, row = quad*4 + reg   [measured m89/m91]
#pragma unroll
    for (int j = 0; j < 4; ++j) {
        const int col = n0 + wn + j * 16 + lrow;
        const float bj = bias[col];
#pragma unroll
        for (int i = 0; i < 4; ++i) {
            const int rbase = m0 + wm + i * 16 + quad * 4;
#pragma unroll
            for (int r = 0; r < 4; ++r)
                C[(size_t)(rbase + r) * N_DIM + col] = acc[i][j][r] + bj;
        }
    }
}

// ---------------------------------------------------------------- fallback (ws too small)
__global__ __launch_bounds__(256) void naive_gemm(const float* __restrict__ A,
                                                  const float* __restrict__ W,
                                                  const float* __restrict__ bias,
                                                  float* __restrict__ C) {
    const int col = blockIdx.x * 16 + threadIdx.x;
    const int row = blockIdx.y * 16 + threadIdx.y;
    float s = 0.f;
    for (int k = 0; k < K_DIM; ++k)
        s += A[(size_t)row * K_DIM + k] * W[(size_t)k * N_DIM + col];
    C[(size_t)row * N_DIM + col] = s + bias[col];
}

extern "C" void kernel_launch(void* const* d_in, const int* in_sizes, int n_in,
                              void* d_out, int out_size, void* d_ws, size_t ws_size,
                              hipStream_t stream) {
    const float* A = (const float*)d_in[0];
    const float* W = (const float*)d_in[1];
    const float* bias = (const float*)d_in[2];
    float* out = (float*)d_out;

    const size_t need = (size_t)2 * M_DIM * K_DIM * sizeof(unsigned short);  // 67 MB
    if (ws_size >= need) {
        unsigned short* Abf = (unsigned short*)d_ws;
        unsigned short* Wt = Abf + (size_t)M_DIM * K_DIM;

        prep<<<4096, 256, 0, stream>>>(A, Abf, W, Wt);
        gemm_bf16<<<(M_DIM / BM) * (N_DIM / BN), 256, 0, stream>>>(Abf, Wt, bias, out);
    } else {
        naive_gemm<<<dim3(N_DIM / 16, M_DIM / 16), dim3(16, 16), 0, stream>>>(A, W, bias, out);
    }
}